// Round 8
// baseline (417.358 us; speedup 1.0000x reference)
//
#include <hip/hip_runtime.h>
#include <hip/hip_bf16.h>
#include <math.h>

#define NEG_SLOPE 0.2f
#define PCAP 131072   // per-partition edge capacity (expected ~106.6k)

typedef __attribute__((ext_vector_type(8))) short bf16x8;
typedef __attribute__((ext_vector_type(4))) float f32x4;

__device__ __forceinline__ float lrelu(float x) { return fmaxf(x, NEG_SLOPE * x); }
__device__ __forceinline__ float blo(unsigned u) { return __uint_as_float(u << 16); }
__device__ __forceinline__ float bhi(unsigned u) { return __uint_as_float(u & 0xffff0000u); }
__device__ __forceinline__ unsigned short f2b(float f) {
    __hip_bfloat16 b = __float2bfloat16(f);
    return *(unsigned short*)&b;
}
// stored-order k -> true k (permutation within each 64-channel block; see R3 note)
__device__ __forceinline__ int ktrue(int k) {
    int pl = k & 63;
    return (k & ~63) + ((pl & 3) << 4) + (pl >> 2);
}

// R8: (1) partition payload packed to ONE uint per edge (dlocal<<16 | s; valid
// since n<=65536 and PN<8192 for this fixed input; overflow path keeps full
// uint2) -> halves prep bucket writes + pass-B reads (R7's prep regression).
// (2) csr stores s*512 byte-offsets -> gather1/gather2 address math is
// shift+add only. (3) gather1 pipeline depth 4->6, lrelu via fmax.

// ---------- prep: W1->W1T bf16, W2->W2T bf16 (k-permuted), deg histogram +
// ---------- dst-partition bucketing ----------
__global__ __launch_bounds__(256) void prep_kernel(
    const float* __restrict__ W1, unsigned short* __restrict__ W1T,
    const float* __restrict__ W2, unsigned short* __restrict__ W2T,
    const int* __restrict__ ei, int E, int EL, int* __restrict__ deg,
    int* __restrict__ pfill, int* __restrict__ ofill,
    unsigned* __restrict__ pedges, uint2* __restrict__ oedges,
    int PN, int b_cw)
{
    const int b = blockIdx.x;
    if (b < b_cw) {
        int i = b * 256 + threadIdx.x;
        if (i < 512 * 256) {
            int nn = i >> 8, k = i & 255;
            W1T[nn * 256 + k] = f2b(W1[k * 512 + nn]);
        } else if (i < 512 * 256 + 32 * 512) {
            int j = i - 512 * 256;
            int c = j >> 9, k = j & 511;
            W2T[c * 512 + k] = f2b(W2[ktrue(k) * 32 + c]);
        }
        return;
    }
    __shared__ int lcnt[8];
    __shared__ int lbase[8];
    const int tid = threadIdx.x;
    const int base = (b - b_cw) * 1024 + tid;
    const int e0 = base, e1 = base + 256, e2 = base + 512, e3 = base + 768;
    const bool v0 = e0 < EL, v1 = e1 < EL, v2 = e2 < EL, v3 = e3 < EL;
    int s0 = 0, s1 = 0, s2 = 0, s3 = 0;
    int d0 = 0, d1 = 0, d2 = 0, d3 = 0;
    if (v0) { if (e0 < E) { s0 = ei[e0]; d0 = ei[E + e0]; } else s0 = d0 = e0 - E; }
    if (v1) { if (e1 < E) { s1 = ei[e1]; d1 = ei[E + e1]; } else s1 = d1 = e1 - E; }
    if (v2) { if (e2 < E) { s2 = ei[e2]; d2 = ei[E + e2]; } else s2 = d2 = e2 - E; }
    if (v3) { if (e3 < E) { s3 = ei[e3]; d3 = ei[E + e3]; } else s3 = d3 = e3 - E; }
    if (v0) atomicAdd(&deg[d0 << 4], 1);
    if (v1) atomicAdd(&deg[d1 << 4], 1);
    if (v2) atomicAdd(&deg[d2 << 4], 1);
    if (v3) atomicAdd(&deg[d3 << 4], 1);
    // partition bucketing with per-block reservation
    if (tid < 8) lcnt[tid] = 0;
    __syncthreads();
    int q0 = 0, q1 = 0, q2 = 0, q3 = 0;
    int r0 = 0, r1 = 0, r2 = 0, r3 = 0;
    if (v0) { q0 = d0 / PN; r0 = atomicAdd(&lcnt[q0], 1); }
    if (v1) { q1 = d1 / PN; r1 = atomicAdd(&lcnt[q1], 1); }
    if (v2) { q2 = d2 / PN; r2 = atomicAdd(&lcnt[q2], 1); }
    if (v3) { q3 = d3 / PN; r3 = atomicAdd(&lcnt[q3], 1); }
    __syncthreads();
    if (tid < 8) lbase[tid] = atomicAdd(&pfill[tid << 4], lcnt[tid]);
    __syncthreads();
    if (v0) { int sl = lbase[q0] + r0;
        if (sl < PCAP) pedges[(size_t)q0 * PCAP + sl] = ((unsigned)(d0 - q0 * PN) << 16) | (unsigned)s0;
        else { int os = atomicAdd(&ofill[0], 1); oedges[os] = make_uint2((unsigned)s0, (unsigned)d0); } }
    if (v1) { int sl = lbase[q1] + r1;
        if (sl < PCAP) pedges[(size_t)q1 * PCAP + sl] = ((unsigned)(d1 - q1 * PN) << 16) | (unsigned)s1;
        else { int os = atomicAdd(&ofill[0], 1); oedges[os] = make_uint2((unsigned)s1, (unsigned)d1); } }
    if (v2) { int sl = lbase[q2] + r2;
        if (sl < PCAP) pedges[(size_t)q2 * PCAP + sl] = ((unsigned)(d2 - q2 * PN) << 16) | (unsigned)s2;
        else { int os = atomicAdd(&ofill[0], 1); oedges[os] = make_uint2((unsigned)s2, (unsigned)d2); } }
    if (v3) { int sl = lbase[q3] + r3;
        if (sl < PCAP) pedges[(size_t)q3 * PCAP + sl] = ((unsigned)(d3 - q3 * PN) << 16) | (unsigned)s3;
        else { int os = atomicAdd(&ofill[0], 1); oedges[os] = make_uint2((unsigned)s3, (unsigned)d3); } }
}

// ---------- two-level scan (reads padded deg) ----------
__global__ __launch_bounds__(256) void scan1_kernel(
    const int* __restrict__ deg, int* __restrict__ bsum, int n)
{
    __shared__ int red[256];
    int t = threadIdx.x, i = blockIdx.x * 256 + t;
    red[t] = (i < n) ? deg[i << 4] : 0;
    __syncthreads();
    for (int off = 128; off > 0; off >>= 1) {
        if (t < off) red[t] += red[t + off];
        __syncthreads();
    }
    if (t == 0) bsum[blockIdx.x] = red[0];
}

__global__ __launch_bounds__(256) void scan2_kernel(
    const int* __restrict__ bsum, int* __restrict__ bsoff, int B)
{
    __shared__ int part[256];
    int t = threadIdx.x;
    int v = (t < B) ? bsum[t] : 0;
    part[t] = v;
    __syncthreads();
    for (int off = 1; off < 256; off <<= 1) {
        int tmp = (t >= off) ? part[t - off] : 0;
        __syncthreads();
        part[t] += tmp;
        __syncthreads();
    }
    if (t < B) bsoff[t] = part[t] - v;
}

__global__ __launch_bounds__(256) void scan3_kernel(
    const int* __restrict__ deg, const int* __restrict__ bsoff,
    int* __restrict__ rowptr, int* __restrict__ cursor, int n, int EL)
{
    __shared__ int part[256];
    int t = threadIdx.x, b = blockIdx.x, i = b * 256 + t;
    int v = (i < n) ? deg[i << 4] : 0;
    part[t] = v;
    __syncthreads();
    for (int off = 1; off < 256; off <<= 1) {
        int tmp = (t >= off) ? part[t - off] : 0;
        __syncthreads();
        part[t] += tmp;
        __syncthreads();
    }
    if (i < n) {
        int r = bsoff[b] + part[t] - v;
        rowptr[i] = r;
        cursor[i << 4] = r;
    }
    if (i == n - 1) rowptr[n] = EL;
}

// ---------- merged XCD-local CSR-scatter (pass B) + GEMM1 ----------
// blocks [0, b_sc): pass B, block bid%8==p drains partition p (XCD-local
// cursor atomics + csr writes). csr stores s*512 byte offsets.
// blocks [b_sc, ...): GEMM1 tiles (128x128, BK=32, int8 quant epilogue).
__global__ __launch_bounds__(256) void scatter_gemm1_kernel(
    const unsigned* __restrict__ pedges, const uint2* __restrict__ oedges,
    const int* __restrict__ pfill, const int* __restrict__ ofill,
    int* __restrict__ cursor, int* __restrict__ csr_off,
    const float* __restrict__ x, const unsigned short* __restrict__ W1T,
    unsigned char* __restrict__ xl1q, float* __restrict__ ascale,
    const float* __restrict__ att_src, const float* __restrict__ att_dst,
    float* __restrict__ a_dst,
    int M, int PN, int b_sc)
{
    if (blockIdx.x < b_sc) {
        const int tid = threadIdx.x;
        const int p   = blockIdx.x & 7;
        const int bi  = blockIdx.x >> 3;
        const int str = (b_sc >> 3) * 256;
        const int pbase = p * PN;
        int cnt = pfill[p << 4]; if (cnt > PCAP) cnt = PCAP;
        const unsigned* pe = pedges + (size_t)p * PCAP;
        for (int i0 = bi * 256 + tid; i0 < cnt; i0 += 4 * str) {
            const int i1 = i0 + str, i2 = i0 + 2 * str, i3 = i0 + 3 * str;
            const bool w1 = i1 < cnt, w2 = i2 < cnt, w3 = i3 < cnt;
            unsigned u0 = pe[i0];
            unsigned u1 = w1 ? pe[i1] : u0;
            unsigned u2 = w2 ? pe[i2] : u0;
            unsigned u3 = w3 ? pe[i3] : u0;
            int p0 = atomicAdd(&cursor[(pbase + (int)(u0 >> 16)) << 4], 1);
            int p1 = w1 ? atomicAdd(&cursor[(pbase + (int)(u1 >> 16)) << 4], 1) : 0;
            int p2 = w2 ? atomicAdd(&cursor[(pbase + (int)(u2 >> 16)) << 4], 1) : 0;
            int p3 = w3 ? atomicAdd(&cursor[(pbase + (int)(u3 >> 16)) << 4], 1) : 0;
            csr_off[p0] = (int)((u0 & 0xffffu) << 9);
            if (w1) csr_off[p1] = (int)((u1 & 0xffffu) << 9);
            if (w2) csr_off[p2] = (int)((u2 & 0xffffu) << 9);
            if (w3) csr_off[p3] = (int)((u3 & 0xffffu) << 9);
        }
        // overflow drain (correctness fallback; empty for this input)
        if (p == 0) {
            int oc = ofill[0];
            for (int i = bi * 256 + tid; i < oc; i += str) {
                uint2 ed = oedges[i];
                int pos = atomicAdd(&cursor[ed.y << 4], 1);
                csr_off[pos] = (int)(ed.x << 9);
            }
        }
        return;
    }
    __shared__ unsigned short As[128 * 40];
    __shared__ unsigned short Bs[128 * 40];
    const int tt  = blockIdx.x - b_sc;
    const int nt4 = gridDim.x - b_sc;
    int tr, tc;
    if (tt < (nt4 & ~31)) { tr = ((tt >> 5) << 3) + (tt & 7); tc = (tt >> 3) & 3; }
    else                  { tr = tt >> 2;                      tc = tt & 3; }
    const int row0 = tr * 128;
    const int col0 = tc * 128;
    const int tid  = threadIdx.x;
    const int wave = tid >> 6;
    const int wrow = wave >> 1;
    const int wcol = wave & 1;
    const int lane = tid & 63;
    const int quad = lane >> 4;
    const int l15  = lane & 15;
    const int sm = tid >> 1;
    const int sk = (tid & 1) * 16;

    f32x4 acc[4][4] = {};

    for (int kb = 0; kb < 256; kb += 32) {
        uint4 a0 = make_uint4(0, 0, 0, 0), a1 = make_uint4(0, 0, 0, 0);
        if (row0 + sm < M) {
            const float4* ap = (const float4*)(x + (size_t)(row0 + sm) * 256 + kb + sk);
            float4 f0 = ap[0], f1 = ap[1], f2 = ap[2], f3 = ap[3];
            a0.x = (unsigned)f2b(f0.x) | ((unsigned)f2b(f0.y) << 16);
            a0.y = (unsigned)f2b(f0.z) | ((unsigned)f2b(f0.w) << 16);
            a0.z = (unsigned)f2b(f1.x) | ((unsigned)f2b(f1.y) << 16);
            a0.w = (unsigned)f2b(f1.z) | ((unsigned)f2b(f1.w) << 16);
            a1.x = (unsigned)f2b(f2.x) | ((unsigned)f2b(f2.y) << 16);
            a1.y = (unsigned)f2b(f2.z) | ((unsigned)f2b(f2.w) << 16);
            a1.z = (unsigned)f2b(f3.x) | ((unsigned)f2b(f3.y) << 16);
            a1.w = (unsigned)f2b(f3.z) | ((unsigned)f2b(f3.w) << 16);
        }
        uint4* adp = (uint4*)&As[sm * 40 + sk];
        adp[0] = a0; adp[1] = a1;
        const uint4* bp = (const uint4*)(W1T + (size_t)(col0 + sm) * 256 + kb + sk);
        uint4* bd = (uint4*)&Bs[sm * 40 + sk];
        bd[0] = bp[0]; bd[1] = bp[1];
        __syncthreads();
        bf16x8 af[4], bf[4];
        #pragma unroll
        for (int mf = 0; mf < 4; ++mf)
            af[mf] = *(const bf16x8*)&As[(wrow * 64 + mf * 16 + l15) * 40 + quad * 8];
        #pragma unroll
        for (int nf = 0; nf < 4; ++nf)
            bf[nf] = *(const bf16x8*)&Bs[(wcol * 64 + nf * 16 + l15) * 40 + quad * 8];
        #pragma unroll
        for (int mf = 0; mf < 4; ++mf)
            #pragma unroll
            for (int nf = 0; nf < 4; ++nf)
                acc[mf][nf] = __builtin_amdgcn_mfma_f32_16x16x32_bf16(
                    af[mf], bf[nf], acc[mf][nf], 0, 0, 0);
        __syncthreads();
    }

    const int h = tc * 2 + wcol;   // head index == 64-col chunk index
    float asv[4], adv[4];
    #pragma unroll
    for (int nf = 0; nf < 4; ++nf) {
        asv[nf] = att_src[h * 64 + nf * 16 + l15];
        adv[nf] = att_dst[h * 64 + nf * 16 + l15];
    }
    #pragma unroll
    for (int mf = 0; mf < 4; ++mf) {
        #pragma unroll
        for (int r = 0; r < 4; ++r) {
            const int row = row0 + wrow * 64 + mf * 16 + quad * 4 + r;
            float v0 = acc[mf][0][r], v1 = acc[mf][1][r];
            float v2 = acc[mf][2][r], v3 = acc[mf][3][r];
            float sv = v0 * asv[0] + v1 * asv[1] + v2 * asv[2] + v3 * asv[3];
            float tv = v0 * adv[0] + v1 * adv[1] + v2 * adv[2] + v3 * adv[3];
            sv += __shfl_xor(sv, 1); tv += __shfl_xor(tv, 1);
            sv += __shfl_xor(sv, 2); tv += __shfl_xor(tv, 2);
            sv += __shfl_xor(sv, 4); tv += __shfl_xor(tv, 4);
            sv += __shfl_xor(sv, 8); tv += __shfl_xor(tv, 8);
            // per-(row, 64-col) absmax across the 16 lanes of this quad
            float m4 = fmaxf(fmaxf(fabsf(v0), fabsf(v1)), fmaxf(fabsf(v2), fabsf(v3)));
            m4 = fmaxf(m4, __shfl_xor(m4, 1));
            m4 = fmaxf(m4, __shfl_xor(m4, 2));
            m4 = fmaxf(m4, __shfl_xor(m4, 4));
            m4 = fmaxf(m4, __shfl_xor(m4, 8));
            const float invs = (m4 > 0.f) ? 127.f / m4 : 0.f;
            int q0 = __float2int_rn(v0 * invs); q0 = max(-127, min(127, q0));
            int q1 = __float2int_rn(v1 * invs); q1 = max(-127, min(127, q1));
            int q2 = __float2int_rn(v2 * invs); q2 = max(-127, min(127, q2));
            int q3 = __float2int_rn(v3 * invs); q3 = max(-127, min(127, q3));
            unsigned pkq = (unsigned)(q0 + 128) | ((unsigned)(q1 + 128) << 8) |
                           ((unsigned)(q2 + 128) << 16) | ((unsigned)(q3 + 128) << 24);
            if (row < M) {
                *(unsigned*)(xl1q + (size_t)row * 512 + h * 64 + l15 * 4) = pkq;
                if (l15 == 0) {
                    *(float2*)(ascale + (size_t)row * 16 + h * 2) =
                        make_float2(sv, m4 * (1.f / 127.f));
                    a_dst[row * 8 + h] = tv;
                }
            }
        }
    }
}

// ---------- fused layer-1 softmax + aggregate + bias + relu -> h1 (bf16) ----------
// R8: 6-deep register pipeline (12 gathers in flight/lane), byte-offset csr
// (shift+add addressing), fmax-form lrelu.
__global__ __launch_bounds__(256) void gather1_kernel(
    const int* __restrict__ rowptr, const int* __restrict__ csr_off,
    const unsigned char* __restrict__ xl1q, const float* __restrict__ ascale,
    const float* __restrict__ a_dst, const float* __restrict__ b1,
    unsigned short* __restrict__ h1, int M)
{
    int wid  = (blockIdx.x * blockDim.x + threadIdx.x) >> 6;
    int lane = threadIdx.x & 63;
    if (wid >= M) return;
    const int start = rowptr[wid], end = rowptr[wid + 1];
    const int h0 = lane >> 3;   // chunk index == head for this lane's 8 channels
    const float adh = a_dst[wid * 8 + h0];
    const char* asbase = (const char*)ascale + (h0 << 3);
    const unsigned char* xbase = xl1q + (lane << 3);
    float dsum = 0.f, csum = 0.f;
    float acc0 = 0.f, acc1 = 0.f, acc2 = 0.f, acc3 = 0.f;
    float acc4 = 0.f, acc5 = 0.f, acc6 = 0.f, acc7 = 0.f;

#define G1_LOAD(AS, V, idx) do {                                              \
        if ((idx) < end) {                                                    \
            int o_ = csr_off[idx];                                            \
            AS = *(const float2*)(asbase + (o_ >> 3));                        \
            V  = *(const uint2*)(xbase + o_);                                 \
        } else { AS = make_float2(-1e30f, 0.f); V = make_uint2(0u, 0u); }     \
    } while (0)

#define G1_CONS(AS, V) do {                                                   \
        float x_ = (AS).x + adh;                                              \
        float p_ = __expf(fmaxf(x_, NEG_SLOPE * x_));                         \
        dsum += p_;                                                           \
        float sa_ = p_ * (AS).y;                                              \
        csum += sa_;                                                          \
        acc0 += (float)( (V).x        & 0xffu) * sa_;                         \
        acc1 += (float)(((V).x >>  8) & 0xffu) * sa_;                         \
        acc2 += (float)(((V).x >> 16) & 0xffu) * sa_;                         \
        acc3 += (float)( (V).x >> 24         ) * sa_;                         \
        acc4 += (float)( (V).y        & 0xffu) * sa_;                         \
        acc5 += (float)(((V).y >>  8) & 0xffu) * sa_;                         \
        acc6 += (float)(((V).y >> 16) & 0xffu) * sa_;                         \
        acc7 += (float)( (V).y >> 24         ) * sa_;                         \
    } while (0)

    float2 as0, as1, as2, as3, as4, as5;
    uint2  v0, v1, v2, v3, v4, v5;
    G1_LOAD(as0, v0, start);
    G1_LOAD(as1, v1, start + 1);
    G1_LOAD(as2, v2, start + 2);
    G1_LOAD(as3, v3, start + 3);
    G1_LOAD(as4, v4, start + 4);
    G1_LOAD(as5, v5, start + 5);
    for (int j = start; j < end; j += 6) {
        float2 na0, na1, na2, na3, na4, na5;
        uint2  nv0, nv1, nv2, nv3, nv4, nv5;
        G1_LOAD(na0, nv0, j + 6);
        G1_LOAD(na1, nv1, j + 7);
        G1_LOAD(na2, nv2, j + 8);
        G1_LOAD(na3, nv3, j + 9);
        G1_LOAD(na4, nv4, j + 10);
        G1_LOAD(na5, nv5, j + 11);
        G1_CONS(as0, v0);
        G1_CONS(as1, v1);
        G1_CONS(as2, v2);
        G1_CONS(as3, v3);
        G1_CONS(as4, v4);
        G1_CONS(as5, v5);
        as0 = na0; v0 = nv0; as1 = na1; v1 = nv1; as2 = na2; v2 = nv2;
        as3 = na3; v3 = nv3; as4 = na4; v4 = nv4; as5 = na5; v5 = nv5;
    }
#undef G1_LOAD
#undef G1_CONS

    const float inv = 1.f / (dsum + 1e-16f);
    const float c128 = 128.f * csum;
    // bias through the stored-order permutation
    const int pg = lane << 3;
    float bj[8];
    #pragma unroll
    for (int j = 0; j < 8; ++j) {
        int pl = (pg + j) & 63;
        bj[j] = b1[(pg & ~63) + ((pl & 3) << 4) + (pl >> 2)];
    }
    float o0 = fmaxf((acc0 - c128) * inv + bj[0], 0.f);
    float o1 = fmaxf((acc1 - c128) * inv + bj[1], 0.f);
    float o2 = fmaxf((acc2 - c128) * inv + bj[2], 0.f);
    float o3 = fmaxf((acc3 - c128) * inv + bj[3], 0.f);
    float o4 = fmaxf((acc4 - c128) * inv + bj[4], 0.f);
    float o5 = fmaxf((acc5 - c128) * inv + bj[5], 0.f);
    float o6 = fmaxf((acc6 - c128) * inv + bj[6], 0.f);
    float o7 = fmaxf((acc7 - c128) * inv + bj[7], 0.f);
    uint4 pk;
    pk.x = (unsigned)f2b(o0) | ((unsigned)f2b(o1) << 16);
    pk.y = (unsigned)f2b(o2) | ((unsigned)f2b(o3) << 16);
    pk.z = (unsigned)f2b(o4) | ((unsigned)f2b(o5) << 16);
    pk.w = (unsigned)f2b(o6) | ((unsigned)f2b(o7) << 16);
    ((uint4*)(h1 + (size_t)wid * 512))[lane] = pk;
}

// ---------- GEMM2 (MFMA bf16): xl2[M,32] = h1[M,512] @ W2; fused att2 dots ----------
__global__ __launch_bounds__(256) void gemm2_mfma_kernel(
    const unsigned short* __restrict__ h1, const unsigned short* __restrict__ W2T,
    const float* __restrict__ att_src2, const float* __restrict__ att_dst2,
    unsigned short* __restrict__ xl2b, float* __restrict__ a_src2, float* __restrict__ a_dst2,
    int M)
{
    __shared__ unsigned short As[128 * 72];
    __shared__ unsigned short Bs[32 * 72];
    const int tid  = threadIdx.x;
    const int row0 = blockIdx.x * 128;
    const int wv   = tid >> 6;
    const int lane = tid & 63;
    const int quad = lane >> 4;
    const int l15  = lane & 15;

    f32x4 acc[2][2] = {};

    for (int kb = 0; kb < 512; kb += 64) {
        #pragma unroll
        for (int i = 0; i < 4; ++i) {
            int u = tid + 256 * i;
            int r = u >> 3;
            int kq = (u & 7) * 8;
            uint4 v = make_uint4(0, 0, 0, 0);
            if (row0 + r < M)
                v = *(const uint4*)(h1 + (size_t)(row0 + r) * 512 + kb + kq);
            *(uint4*)&As[r * 72 + kq] = v;
        }
        {
            int r = tid >> 3;
            int kq = (tid & 7) * 8;
            *(uint4*)&Bs[r * 72 + kq] = *(const uint4*)(W2T + (size_t)r * 512 + kb + kq);
        }
        __syncthreads();

        #pragma unroll
        for (int ks = 0; ks < 2; ++ks) {
            bf16x8 af[2], bf[2];
            #pragma unroll
            for (int mf = 0; mf < 2; ++mf)
                af[mf] = *(const bf16x8*)&As[(wv * 32 + mf * 16 + l15) * 72 + ks * 32 + quad * 8];
            #pragma unroll
            for (int nf = 0; nf < 2; ++nf)
                bf[nf] = *(const bf16x8*)&Bs[(nf * 16 + l15) * 72 + ks * 32 + quad * 8];
            #pragma unroll
            for (int mf = 0; mf < 2; ++mf)
                #pragma unroll
                for (int nf = 0; nf < 2; ++nf)
                    acc[mf][nf] = __builtin_amdgcn_mfma_f32_16x16x32_bf16(
                        af[mf], bf[nf], acc[mf][nf], 0, 0, 0);
        }
        __syncthreads();
    }

    float as2v[2], ad2v[2];
    #pragma unroll
    for (int nf = 0; nf < 2; ++nf) {
        as2v[nf] = att_src2[nf * 16 + l15];
        ad2v[nf] = att_dst2[nf * 16 + l15];
    }
    #pragma unroll
    for (int mf = 0; mf < 2; ++mf) {
        #pragma unroll
        for (int r = 0; r < 4; ++r) {
            const int row = row0 + wv * 32 + mf * 16 + quad * 4 + r;
            float v0 = acc[mf][0][r], v1 = acc[mf][1][r];
            float sv = v0 * as2v[0] + v1 * as2v[1];
            float tv = v0 * ad2v[0] + v1 * ad2v[1];
            sv += __shfl_xor(sv, 1); tv += __shfl_xor(tv, 1);
            sv += __shfl_xor(sv, 2); tv += __shfl_xor(tv, 2);
            sv += __shfl_xor(sv, 4); tv += __shfl_xor(tv, 4);
            sv += __shfl_xor(sv, 8); tv += __shfl_xor(tv, 8);
            if (row < M) {
                xl2b[(size_t)row * 32 + l15]      = f2b(v0);
                xl2b[(size_t)row * 32 + 16 + l15] = f2b(v1);
                if (l15 == 0) { a_src2[row] = sv; a_dst2[row] = tv; }
            }
        }
    }
}

// ---------- fused layer-2 softmax + aggregate + bias + relu + fc head ----------
// depth-2 prefetch per edge-slot group; byte-offset csr addressing.
__global__ __launch_bounds__(256) void gather2_head_kernel(
    const int* __restrict__ rowptr, const int* __restrict__ csr_off,
    const unsigned short* __restrict__ xl2b, const float* __restrict__ a_src2,
    const float* __restrict__ a_dst2, const float* __restrict__ b2,
    const float* __restrict__ fcW, const float* __restrict__ fcb,
    float* __restrict__ emb, float* __restrict__ logits, int M)
{
    __shared__ float sw[32][40];
    for (int i = threadIdx.x; i < 32 * 40; i += 256) sw[i / 40][i % 40] = fcW[i];
    __syncthreads();
    int wid  = (blockIdx.x * blockDim.x + threadIdx.x) >> 6;
    int lane = threadIdx.x & 63;
    if (wid >= M) return;
    const int start = rowptr[wid], end = rowptr[wid + 1];
    const float ad = a_dst2[wid];
    const int g  = lane >> 4;        // 0..3: edge slot
    const int c2 = lane & 15;        // channel pair
    const char* xbase = (const char*)xl2b + (c2 << 2);

#define G2_LOAD(A, U, idx) do {                                               \
        if ((idx) < end) {                                                    \
            int o_ = csr_off[idx];                                            \
            A = *(const float*)((const char*)a_src2 + (o_ >> 7));             \
            U = *(const unsigned*)(xbase + (o_ >> 3));                        \
        } else { A = -1e30f; U = 0u; }                                        \
    } while (0)

    float dsum = 0.f;
    float accx = 0.f, accy = 0.f;
    float a0, a1;
    unsigned u0, u1;
    G2_LOAD(a0, u0, start + g);
    G2_LOAD(a1, u1, start + g + 4);
    for (int j = start + g; j < end; j += 8) {
        float na0, na1;
        unsigned nu0, nu1;
        G2_LOAD(na0, nu0, j + 8);
        G2_LOAD(na1, nu1, j + 12);
        {
            float xv = a0 + ad;
            float p = __expf(fmaxf(xv, NEG_SLOPE * xv));
            dsum += p;
            accx += p * blo(u0);
            accy += p * bhi(u0);
        }
        {
            float xv = a1 + ad;
            float p = __expf(fmaxf(xv, NEG_SLOPE * xv));
            dsum += p;
            accx += p * blo(u1);
            accy += p * bhi(u1);
        }
        a0 = na0; u0 = nu0; a1 = na1; u1 = nu1;
    }
#undef G2_LOAD
    dsum += __shfl_xor(dsum, 16); accx += __shfl_xor(accx, 16); accy += __shfl_xor(accy, 16);
    dsum += __shfl_xor(dsum, 32); accx += __shfl_xor(accx, 32); accy += __shfl_xor(accy, 32);
    const float inv = 1.f / (dsum + 1e-16f);
    const float2 b2v = *(const float2*)(b2 + 2 * c2);
    float ex = fmaxf(accx * inv + b2v.x, 0.f);
    float ey = fmaxf(accy * inv + b2v.y, 0.f);
    if (g == 0) *(float2*)(emb + (size_t)wid * 32 + 2 * c2) = make_float2(ex, ey);
    const int col = (lane < 40) ? lane : 0;
    float lsum = (lane < 40) ? fcb[col] : 0.f;
    #pragma unroll
    for (int k = 0; k < 16; ++k) {
        float vx = __shfl(ex, k);
        float vy = __shfl(ey, k);
        lsum += vx * sw[2 * k][col] + vy * sw[2 * k + 1][col];
    }
    if (lane < 40) logits[(size_t)wid * 40 + lane] = lsum;
}

// ---------- launch ----------
extern "C" void kernel_launch(void* const* d_in, const int* in_sizes, int n_in,
                              void* d_out, int out_size, void* d_ws, size_t ws_size,
                              hipStream_t stream)
{
    const float* x   = (const float*)d_in[0];
    const int*   ei  = (const int*)d_in[1];
    const float* W1  = (const float*)d_in[2];
    const float* as1 = (const float*)d_in[3];
    const float* ad1 = (const float*)d_in[4];
    const float* b1  = (const float*)d_in[5];
    const float* W2  = (const float*)d_in[6];
    const float* as2 = (const float*)d_in[7];
    const float* ad2 = (const float*)d_in[8];
    const float* b2  = (const float*)d_in[9];
    const float* fcW = (const float*)d_in[10];
    const float* fcb = (const float*)d_in[11];

    const int n  = in_sizes[0] / 256;   // 50000 (pack assumes n <= 65536)
    const int e  = in_sizes[1] / 2;     // 800000
    const int el = e + n;               // with self-loops
    const int pn = (((n + 7) / 8) + 63) & ~63;   // 6272 (pack assumes pn < 65536)

    char* ws = (char*)d_ws;
    size_t off = 0;
    unsigned short* w1t  = (unsigned short*)(ws + off); off += (size_t)512 * 256 * 2;
    unsigned short* w2t  = (unsigned short*)(ws + off); off += (size_t)32 * 512 * 2;
    unsigned char*  xl1q = (unsigned char*)(ws + off);  off += (size_t)n * 512;
    float* ascale = (float*)(ws + off); off += (size_t)n * 16 * 4;
    unsigned short* h1   = (unsigned short*)(ws + off); off += (size_t)n * 512 * 2;
    unsigned short* xl2b = (unsigned short*)(ws + off); off += (size_t)n * 32 * 2;
    float* a_dst1 = (float*)(ws + off); off += (size_t)n * 8 * 4;
    float* a_src2 = (float*)(ws + off); off += (size_t)n * 4;
    float* a_dst2 = (float*)(ws + off); off += (size_t)n * 4;
    int*   deg    = (int*)(ws + off);   off += (size_t)n * 16 * 4;   // padded: 1/line
    int*   pfill  = (int*)(ws + off);   off += 8 * 16 * 4;           // padded: 1/line
    int*   ofill  = (int*)(ws + off);   off += 16 * 4;
    int*   cursor = (int*)(ws + off);   off += (size_t)n * 16 * 4;   // padded: 1/line
    int*   rowptr = (int*)(ws + off);   off += (size_t)(n + 1) * 4;
    int*   csr_off= (int*)(ws + off);   off += (size_t)el * 4;
    int*   bsum   = (int*)(ws + off);   off += 256 * 4;
    int*   bsoff  = (int*)(ws + off);   off += 256 * 4;

    // part_edges/oedges ALIAS h1 (dead until gather1 writes it).
    unsigned* pedges = (unsigned*)h1;                       // 8 * PCAP * 4 B = 4.2 MB
    uint2* oedges = (uint2*)((char*)h1 + (size_t)8 * PCAP * 4);

    float* emb    = (float*)d_out;
    float* logits = (float*)d_out + (size_t)n * 32;

    // zero deg + pfill + ofill in one shot (contiguous)
    hipMemsetAsync(deg, 0, ((size_t)n * 16 + 8 * 16 + 16) * 4, stream);

    const int b_cw = (512 * 256 + 32 * 512 + 255) / 256;
    const int b_dg = (el + 1023) / 1024;
    prep_kernel<<<b_cw + b_dg, 256, 0, stream>>>(
        W1, w1t, W2, w2t, ei, e, el, deg, pfill, ofill, pedges, oedges, pn, b_cw);

    const int nb = (n + 255) / 256;
    scan1_kernel<<<nb, 256, 0, stream>>>(deg, bsum, n);
    scan2_kernel<<<1, 256, 0, stream>>>(bsum, bsoff, nb);
    scan3_kernel<<<nb, 256, 0, stream>>>(deg, bsoff, rowptr, cursor, n, el);

    const int b_sc = 832;   // pass-B blocks, multiple of 8 (bid%8 == partition/XCD)
    const int n_tiles_y = (n + 127) / 128;
    scatter_gemm1_kernel<<<b_sc + 4 * n_tiles_y, 256, 0, stream>>>(
        pedges, oedges, pfill, ofill, cursor, csr_off,
        x, w1t, xl1q, ascale, as1, ad1, a_dst1, n, pn, b_sc);

    gather1_kernel<<<((size_t)n * 64 + 255) / 256, 256, 0, stream>>>(
        rowptr, csr_off, xl1q, ascale, a_dst1, b1, h1, n);
    gemm2_mfma_kernel<<<(n + 127) / 128, 256, 0, stream>>>(
        h1, w2t, as2, ad2, xl2b, a_src2, a_dst2, n);
    gather2_head_kernel<<<((size_t)n * 64 + 255) / 256, 256, 0, stream>>>(
        rowptr, csr_off, xl2b, a_src2, a_dst2, b2, fcW, fcb, emb, logits, n);
}

// Round 9
// 391.006 us; speedup vs baseline: 1.0674x; 1.0674x over previous
//
#include <hip/hip_runtime.h>
#include <hip/hip_bf16.h>
#include <math.h>

#define NEG_SLOPE 0.2f

typedef __attribute__((ext_vector_type(8))) short bf16x8;
typedef __attribute__((ext_vector_type(4))) float f32x4;

__device__ __forceinline__ float lrelu(float x) { return fmaxf(x, NEG_SLOPE * x); }
__device__ __forceinline__ float blo(unsigned u) { return __uint_as_float(u << 16); }
__device__ __forceinline__ float bhi(unsigned u) { return __uint_as_float(u & 0xffff0000u); }
__device__ __forceinline__ unsigned short f2b(float f) {
    __hip_bfloat16 b = __float2bfloat16(f);
    return *(unsigned short*)&b;
}
// stored-order k -> true k (permutation within each 64-channel block; see R3 note)
__device__ __forceinline__ int ktrue(int k) {
    int pl = k & 63;
    return (k & ~63) + ((pl & 3) << 4) + (pl >> 2);
}

// R9: revert to the R6 structure (best measured: 391 us). R7's two-phase
// partitioned scatter fixed csr write-amp but its prep bucketing cost more
// than it saved (402); R8's depth-6 gather1 traded occupancy for MLP and
// regressed (417; VGPR 32->40, occ 67->52%). Kept from R8: byte-offset csr
// (shift+add gather addressing), fmax-form lrelu, precomputed lane bases.

// ---------- prep: W1->W1T bf16, W2->W2T bf16 (k-permuted), deg histogram ----------
__global__ __launch_bounds__(256) void prep_kernel(
    const float* __restrict__ W1, unsigned short* __restrict__ W1T,
    const float* __restrict__ W2, unsigned short* __restrict__ W2T,
    const int* __restrict__ ei, int E, int EL, int* __restrict__ deg,
    int b_cw)
{
    const int b = blockIdx.x;
    if (b < b_cw) {
        int i = b * 256 + threadIdx.x;
        if (i < 512 * 256) {
            int nn = i >> 8, k = i & 255;
            W1T[nn * 256 + k] = f2b(W1[k * 512 + nn]);
        } else if (i < 512 * 256 + 32 * 512) {
            int j = i - 512 * 256;
            int c = j >> 9, k = j & 511;
            W2T[c * 512 + k] = f2b(W2[ktrue(k) * 32 + c]);
        }
    } else {
        // histogram: 4 edges/thread, fire-and-forget atomics on padded counters
        int base = (b - b_cw) * 1024 + threadIdx.x;
        #pragma unroll
        for (int k = 0; k < 4; ++k) {
            int e = base + k * 256;
            if (e < EL) {
                int d = (e < E) ? ei[E + e] : e - E;
                atomicAdd(&deg[d << 4], 1);
            }
        }
    }
}

// ---------- two-level scan (reads padded deg) ----------
__global__ __launch_bounds__(256) void scan1_kernel(
    const int* __restrict__ deg, int* __restrict__ bsum, int n)
{
    __shared__ int red[256];
    int t = threadIdx.x, i = blockIdx.x * 256 + t;
    red[t] = (i < n) ? deg[i << 4] : 0;
    __syncthreads();
    for (int off = 128; off > 0; off >>= 1) {
        if (t < off) red[t] += red[t + off];
        __syncthreads();
    }
    if (t == 0) bsum[blockIdx.x] = red[0];
}

__global__ __launch_bounds__(256) void scan2_kernel(
    const int* __restrict__ bsum, int* __restrict__ bsoff, int B)
{
    __shared__ int part[256];
    int t = threadIdx.x;
    int v = (t < B) ? bsum[t] : 0;
    part[t] = v;
    __syncthreads();
    for (int off = 1; off < 256; off <<= 1) {
        int tmp = (t >= off) ? part[t - off] : 0;
        __syncthreads();
        part[t] += tmp;
        __syncthreads();
    }
    if (t < B) bsoff[t] = part[t] - v;
}

__global__ __launch_bounds__(256) void scan3_kernel(
    const int* __restrict__ deg, const int* __restrict__ bsoff,
    int* __restrict__ rowptr, int* __restrict__ cursor, int n, int EL)
{
    __shared__ int part[256];
    int t = threadIdx.x, b = blockIdx.x, i = b * 256 + t;
    int v = (i < n) ? deg[i << 4] : 0;
    part[t] = v;
    __syncthreads();
    for (int off = 1; off < 256; off <<= 1) {
        int tmp = (t >= off) ? part[t - off] : 0;
        __syncthreads();
        part[t] += tmp;
        __syncthreads();
    }
    if (i < n) {
        int r = bsoff[b] + part[t] - v;
        rowptr[i] = r;
        cursor[i << 4] = r;
    }
    if (i == n - 1) rowptr[n] = EL;
}

// ---------- merged CSR-scatter + GEMM1 ----------
// blocks [0, b_sc): scatter 1024 edges each (4/thread, phase-split atomics on
// line-padded cursor). csr stores s*512 byte offsets.
// blocks [b_sc, ...): GEMM1 tiles (128x128, BK=32, rows padded 32->40, fused
// att1 dots, int8 quant epilogue -- R3). ascale = (a_src, scale) float2.
__global__ __launch_bounds__(256) void scatter_gemm1_kernel(
    const int* __restrict__ ei, int E, int EL,
    int* __restrict__ cursor, int* __restrict__ csr_off,
    const float* __restrict__ x, const unsigned short* __restrict__ W1T,
    unsigned char* __restrict__ xl1q, float* __restrict__ ascale,
    const float* __restrict__ att_src, const float* __restrict__ att_dst,
    float* __restrict__ a_dst,
    int M, int b_sc)
{
    if (blockIdx.x < b_sc) {
        const int base = blockIdx.x * 1024 + threadIdx.x;
        int s0 = 0, s1 = 0, s2 = 0, s3 = 0;
        int d0 = 0, d1 = 0, d2 = 0, d3 = 0;
        const int e0 = base, e1 = base + 256, e2 = base + 512, e3 = base + 768;
        if (e0 < EL) { if (e0 < E) { s0 = ei[e0]; d0 = ei[E + e0]; } else s0 = d0 = e0 - E; }
        if (e1 < EL) { if (e1 < E) { s1 = ei[e1]; d1 = ei[E + e1]; } else s1 = d1 = e1 - E; }
        if (e2 < EL) { if (e2 < E) { s2 = ei[e2]; d2 = ei[E + e2]; } else s2 = d2 = e2 - E; }
        if (e3 < EL) { if (e3 < E) { s3 = ei[e3]; d3 = ei[E + e3]; } else s3 = d3 = e3 - E; }
        int p0 = 0, p1 = 0, p2 = 0, p3 = 0;
        if (e0 < EL) p0 = atomicAdd(&cursor[d0 << 4], 1);
        if (e1 < EL) p1 = atomicAdd(&cursor[d1 << 4], 1);
        if (e2 < EL) p2 = atomicAdd(&cursor[d2 << 4], 1);
        if (e3 < EL) p3 = atomicAdd(&cursor[d3 << 4], 1);
        if (e0 < EL) csr_off[p0] = s0 << 9;
        if (e1 < EL) csr_off[p1] = s1 << 9;
        if (e2 < EL) csr_off[p2] = s2 << 9;
        if (e3 < EL) csr_off[p3] = s3 << 9;
        return;
    }
    __shared__ unsigned short As[128 * 40];
    __shared__ unsigned short Bs[128 * 40];
    const int tt  = blockIdx.x - b_sc;
    const int nt4 = gridDim.x - b_sc;
    int tr, tc;
    if (tt < (nt4 & ~31)) { tr = ((tt >> 5) << 3) + (tt & 7); tc = (tt >> 3) & 3; }
    else                  { tr = tt >> 2;                      tc = tt & 3; }
    const int row0 = tr * 128;
    const int col0 = tc * 128;
    const int tid  = threadIdx.x;
    const int wave = tid >> 6;
    const int wrow = wave >> 1;
    const int wcol = wave & 1;
    const int lane = tid & 63;
    const int quad = lane >> 4;
    const int l15  = lane & 15;
    const int sm = tid >> 1;
    const int sk = (tid & 1) * 16;

    f32x4 acc[4][4] = {};

    for (int kb = 0; kb < 256; kb += 32) {
        uint4 a0 = make_uint4(0, 0, 0, 0), a1 = make_uint4(0, 0, 0, 0);
        if (row0 + sm < M) {
            const float4* ap = (const float4*)(x + (size_t)(row0 + sm) * 256 + kb + sk);
            float4 f0 = ap[0], f1 = ap[1], f2 = ap[2], f3 = ap[3];
            a0.x = (unsigned)f2b(f0.x) | ((unsigned)f2b(f0.y) << 16);
            a0.y = (unsigned)f2b(f0.z) | ((unsigned)f2b(f0.w) << 16);
            a0.z = (unsigned)f2b(f1.x) | ((unsigned)f2b(f1.y) << 16);
            a0.w = (unsigned)f2b(f1.z) | ((unsigned)f2b(f1.w) << 16);
            a1.x = (unsigned)f2b(f2.x) | ((unsigned)f2b(f2.y) << 16);
            a1.y = (unsigned)f2b(f2.z) | ((unsigned)f2b(f2.w) << 16);
            a1.z = (unsigned)f2b(f3.x) | ((unsigned)f2b(f3.y) << 16);
            a1.w = (unsigned)f2b(f3.z) | ((unsigned)f2b(f3.w) << 16);
        }
        uint4* adp = (uint4*)&As[sm * 40 + sk];
        adp[0] = a0; adp[1] = a1;
        const uint4* bp = (const uint4*)(W1T + (size_t)(col0 + sm) * 256 + kb + sk);
        uint4* bd = (uint4*)&Bs[sm * 40 + sk];
        bd[0] = bp[0]; bd[1] = bp[1];
        __syncthreads();
        bf16x8 af[4], bf[4];
        #pragma unroll
        for (int mf = 0; mf < 4; ++mf)
            af[mf] = *(const bf16x8*)&As[(wrow * 64 + mf * 16 + l15) * 40 + quad * 8];
        #pragma unroll
        for (int nf = 0; nf < 4; ++nf)
            bf[nf] = *(const bf16x8*)&Bs[(wcol * 64 + nf * 16 + l15) * 40 + quad * 8];
        #pragma unroll
        for (int mf = 0; mf < 4; ++mf)
            #pragma unroll
            for (int nf = 0; nf < 4; ++nf)
                acc[mf][nf] = __builtin_amdgcn_mfma_f32_16x16x32_bf16(
                    af[mf], bf[nf], acc[mf][nf], 0, 0, 0);
        __syncthreads();
    }

    const int h = tc * 2 + wcol;   // head index == 64-col chunk index
    float asv[4], adv[4];
    #pragma unroll
    for (int nf = 0; nf < 4; ++nf) {
        asv[nf] = att_src[h * 64 + nf * 16 + l15];
        adv[nf] = att_dst[h * 64 + nf * 16 + l15];
    }
    #pragma unroll
    for (int mf = 0; mf < 4; ++mf) {
        #pragma unroll
        for (int r = 0; r < 4; ++r) {
            const int row = row0 + wrow * 64 + mf * 16 + quad * 4 + r;
            float v0 = acc[mf][0][r], v1 = acc[mf][1][r];
            float v2 = acc[mf][2][r], v3 = acc[mf][3][r];
            float sv = v0 * asv[0] + v1 * asv[1] + v2 * asv[2] + v3 * asv[3];
            float tv = v0 * adv[0] + v1 * adv[1] + v2 * adv[2] + v3 * adv[3];
            sv += __shfl_xor(sv, 1); tv += __shfl_xor(tv, 1);
            sv += __shfl_xor(sv, 2); tv += __shfl_xor(tv, 2);
            sv += __shfl_xor(sv, 4); tv += __shfl_xor(tv, 4);
            sv += __shfl_xor(sv, 8); tv += __shfl_xor(tv, 8);
            // per-(row, 64-col) absmax across the 16 lanes of this quad
            float m4 = fmaxf(fmaxf(fabsf(v0), fabsf(v1)), fmaxf(fabsf(v2), fabsf(v3)));
            m4 = fmaxf(m4, __shfl_xor(m4, 1));
            m4 = fmaxf(m4, __shfl_xor(m4, 2));
            m4 = fmaxf(m4, __shfl_xor(m4, 4));
            m4 = fmaxf(m4, __shfl_xor(m4, 8));
            const float invs = (m4 > 0.f) ? 127.f / m4 : 0.f;
            int q0 = __float2int_rn(v0 * invs); q0 = max(-127, min(127, q0));
            int q1 = __float2int_rn(v1 * invs); q1 = max(-127, min(127, q1));
            int q2 = __float2int_rn(v2 * invs); q2 = max(-127, min(127, q2));
            int q3 = __float2int_rn(v3 * invs); q3 = max(-127, min(127, q3));
            unsigned pkq = (unsigned)(q0 + 128) | ((unsigned)(q1 + 128) << 8) |
                           ((unsigned)(q2 + 128) << 16) | ((unsigned)(q3 + 128) << 24);
            if (row < M) {
                *(unsigned*)(xl1q + (size_t)row * 512 + h * 64 + l15 * 4) = pkq;
                if (l15 == 0) {
                    *(float2*)(ascale + (size_t)row * 16 + h * 2) =
                        make_float2(sv, m4 * (1.f / 127.f));
                    a_dst[row * 8 + h] = tv;
                }
            }
        }
    }
}

// ---------- fused layer-1 softmax + aggregate + bias + relu -> h1 (bf16) ----------
// depth-4 register pipeline (R6 sweet spot: 32 VGPR, ~67% occupancy; depth 6
// regressed via occupancy loss -- R8). Byte-offset csr addressing.
__global__ __launch_bounds__(256) void gather1_kernel(
    const int* __restrict__ rowptr, const int* __restrict__ csr_off,
    const unsigned char* __restrict__ xl1q, const float* __restrict__ ascale,
    const float* __restrict__ a_dst, const float* __restrict__ b1,
    unsigned short* __restrict__ h1, int M)
{
    int wid  = (blockIdx.x * blockDim.x + threadIdx.x) >> 6;
    int lane = threadIdx.x & 63;
    if (wid >= M) return;
    const int start = rowptr[wid], end = rowptr[wid + 1];
    const int h0 = lane >> 3;   // chunk index == head for this lane's 8 channels
    const float adh = a_dst[wid * 8 + h0];
    const char* asbase = (const char*)ascale + (h0 << 3);
    const unsigned char* xbase = xl1q + (lane << 3);
    float dsum = 0.f, csum = 0.f;
    float acc0 = 0.f, acc1 = 0.f, acc2 = 0.f, acc3 = 0.f;
    float acc4 = 0.f, acc5 = 0.f, acc6 = 0.f, acc7 = 0.f;

#define G1_LOAD(AS, V, idx) do {                                              \
        if ((idx) < end) {                                                    \
            int o_ = csr_off[idx];                                            \
            AS = *(const float2*)(asbase + (o_ >> 3));                        \
            V  = *(const uint2*)(xbase + o_);                                 \
        } else { AS = make_float2(-1e30f, 0.f); V = make_uint2(0u, 0u); }     \
    } while (0)

#define G1_CONS(AS, V) do {                                                   \
        float x_ = (AS).x + adh;                                              \
        float p_ = __expf(fmaxf(x_, NEG_SLOPE * x_));                         \
        dsum += p_;                                                           \
        float sa_ = p_ * (AS).y;                                              \
        csum += sa_;                                                          \
        acc0 += (float)( (V).x        & 0xffu) * sa_;                         \
        acc1 += (float)(((V).x >>  8) & 0xffu) * sa_;                         \
        acc2 += (float)(((V).x >> 16) & 0xffu) * sa_;                         \
        acc3 += (float)( (V).x >> 24         ) * sa_;                         \
        acc4 += (float)( (V).y        & 0xffu) * sa_;                         \
        acc5 += (float)(((V).y >>  8) & 0xffu) * sa_;                         \
        acc6 += (float)(((V).y >> 16) & 0xffu) * sa_;                         \
        acc7 += (float)( (V).y >> 24         ) * sa_;                         \
    } while (0)

    float2 as0, as1, as2, as3;
    uint2  v0, v1, v2, v3;
    G1_LOAD(as0, v0, start);
    G1_LOAD(as1, v1, start + 1);
    G1_LOAD(as2, v2, start + 2);
    G1_LOAD(as3, v3, start + 3);
    for (int j = start; j < end; j += 4) {
        float2 na0, na1, na2, na3;
        uint2  nv0, nv1, nv2, nv3;
        G1_LOAD(na0, nv0, j + 4);
        G1_LOAD(na1, nv1, j + 5);
        G1_LOAD(na2, nv2, j + 6);
        G1_LOAD(na3, nv3, j + 7);
        G1_CONS(as0, v0);
        G1_CONS(as1, v1);
        G1_CONS(as2, v2);
        G1_CONS(as3, v3);
        as0 = na0; v0 = nv0; as1 = na1; v1 = nv1;
        as2 = na2; v2 = nv2; as3 = na3; v3 = nv3;
    }
#undef G1_LOAD
#undef G1_CONS

    const float inv = 1.f / (dsum + 1e-16f);
    const float c128 = 128.f * csum;
    // bias through the stored-order permutation
    const int pg = lane << 3;
    float bj[8];
    #pragma unroll
    for (int j = 0; j < 8; ++j) {
        int pl = (pg + j) & 63;
        bj[j] = b1[(pg & ~63) + ((pl & 3) << 4) + (pl >> 2)];
    }
    float o0 = fmaxf((acc0 - c128) * inv + bj[0], 0.f);
    float o1 = fmaxf((acc1 - c128) * inv + bj[1], 0.f);
    float o2 = fmaxf((acc2 - c128) * inv + bj[2], 0.f);
    float o3 = fmaxf((acc3 - c128) * inv + bj[3], 0.f);
    float o4 = fmaxf((acc4 - c128) * inv + bj[4], 0.f);
    float o5 = fmaxf((acc5 - c128) * inv + bj[5], 0.f);
    float o6 = fmaxf((acc6 - c128) * inv + bj[6], 0.f);
    float o7 = fmaxf((acc7 - c128) * inv + bj[7], 0.f);
    uint4 pk;
    pk.x = (unsigned)f2b(o0) | ((unsigned)f2b(o1) << 16);
    pk.y = (unsigned)f2b(o2) | ((unsigned)f2b(o3) << 16);
    pk.z = (unsigned)f2b(o4) | ((unsigned)f2b(o5) << 16);
    pk.w = (unsigned)f2b(o6) | ((unsigned)f2b(o7) << 16);
    ((uint4*)(h1 + (size_t)wid * 512))[lane] = pk;
}

// ---------- GEMM2 (MFMA bf16): xl2[M,32] = h1[M,512] @ W2; fused att2 dots ----------
__global__ __launch_bounds__(256) void gemm2_mfma_kernel(
    const unsigned short* __restrict__ h1, const unsigned short* __restrict__ W2T,
    const float* __restrict__ att_src2, const float* __restrict__ att_dst2,
    unsigned short* __restrict__ xl2b, float* __restrict__ a_src2, float* __restrict__ a_dst2,
    int M)
{
    __shared__ unsigned short As[128 * 72];
    __shared__ unsigned short Bs[32 * 72];
    const int tid  = threadIdx.x;
    const int row0 = blockIdx.x * 128;
    const int wv   = tid >> 6;
    const int lane = tid & 63;
    const int quad = lane >> 4;
    const int l15  = lane & 15;

    f32x4 acc[2][2] = {};

    for (int kb = 0; kb < 512; kb += 64) {
        #pragma unroll
        for (int i = 0; i < 4; ++i) {
            int u = tid + 256 * i;
            int r = u >> 3;
            int kq = (u & 7) * 8;
            uint4 v = make_uint4(0, 0, 0, 0);
            if (row0 + r < M)
                v = *(const uint4*)(h1 + (size_t)(row0 + r) * 512 + kb + kq);
            *(uint4*)&As[r * 72 + kq] = v;
        }
        {
            int r = tid >> 3;
            int kq = (tid & 7) * 8;
            *(uint4*)&Bs[r * 72 + kq] = *(const uint4*)(W2T + (size_t)r * 512 + kb + kq);
        }
        __syncthreads();

        #pragma unroll
        for (int ks = 0; ks < 2; ++ks) {
            bf16x8 af[2], bf[2];
            #pragma unroll
            for (int mf = 0; mf < 2; ++mf)
                af[mf] = *(const bf16x8*)&As[(wv * 32 + mf * 16 + l15) * 72 + ks * 32 + quad * 8];
            #pragma unroll
            for (int nf = 0; nf < 2; ++nf)
                bf[nf] = *(const bf16x8*)&Bs[(nf * 16 + l15) * 72 + ks * 32 + quad * 8];
            #pragma unroll
            for (int mf = 0; mf < 2; ++mf)
                #pragma unroll
                for (int nf = 0; nf < 2; ++nf)
                    acc[mf][nf] = __builtin_amdgcn_mfma_f32_16x16x32_bf16(
                        af[mf], bf[nf], acc[mf][nf], 0, 0, 0);
        }
        __syncthreads();
    }

    float as2v[2], ad2v[2];
    #pragma unroll
    for (int nf = 0; nf < 2; ++nf) {
        as2v[nf] = att_src2[nf * 16 + l15];
        ad2v[nf] = att_dst2[nf * 16 + l15];
    }
    #pragma unroll
    for (int mf = 0; mf < 2; ++mf) {
        #pragma unroll
        for (int r = 0; r < 4; ++r) {
            const int row = row0 + wv * 32 + mf * 16 + quad * 4 + r;
            float v0 = acc[mf][0][r], v1 = acc[mf][1][r];
            float sv = v0 * as2v[0] + v1 * as2v[1];
            float tv = v0 * ad2v[0] + v1 * ad2v[1];
            sv += __shfl_xor(sv, 1); tv += __shfl_xor(tv, 1);
            sv += __shfl_xor(sv, 2); tv += __shfl_xor(tv, 2);
            sv += __shfl_xor(sv, 4); tv += __shfl_xor(tv, 4);
            sv += __shfl_xor(sv, 8); tv += __shfl_xor(tv, 8);
            if (row < M) {
                xl2b[(size_t)row * 32 + l15]      = f2b(v0);
                xl2b[(size_t)row * 32 + 16 + l15] = f2b(v1);
                if (l15 == 0) { a_src2[row] = sv; a_dst2[row] = tv; }
            }
        }
    }
}

// ---------- fused layer-2 softmax + aggregate + bias + relu + fc head ----------
// depth-2 prefetch per edge-slot group; byte-offset csr addressing.
__global__ __launch_bounds__(256) void gather2_head_kernel(
    const int* __restrict__ rowptr, const int* __restrict__ csr_off,
    const unsigned short* __restrict__ xl2b, const float* __restrict__ a_src2,
    const float* __restrict__ a_dst2, const float* __restrict__ b2,
    const float* __restrict__ fcW, const float* __restrict__ fcb,
    float* __restrict__ emb, float* __restrict__ logits, int M)
{
    __shared__ float sw[32][40];
    for (int i = threadIdx.x; i < 32 * 40; i += 256) sw[i / 40][i % 40] = fcW[i];
    __syncthreads();
    int wid  = (blockIdx.x * blockDim.x + threadIdx.x) >> 6;
    int lane = threadIdx.x & 63;
    if (wid >= M) return;
    const int start = rowptr[wid], end = rowptr[wid + 1];
    const float ad = a_dst2[wid];
    const int g  = lane >> 4;        // 0..3: edge slot
    const int c2 = lane & 15;        // channel pair
    const char* xbase = (const char*)xl2b + (c2 << 2);

#define G2_LOAD(A, U, idx) do {                                               \
        if ((idx) < end) {                                                    \
            int o_ = csr_off[idx];                                            \
            A = *(const float*)((const char*)a_src2 + (o_ >> 7));             \
            U = *(const unsigned*)(xbase + (o_ >> 3));                        \
        } else { A = -1e30f; U = 0u; }                                        \
    } while (0)

    float dsum = 0.f;
    float accx = 0.f, accy = 0.f;
    float a0, a1;
    unsigned u0, u1;
    G2_LOAD(a0, u0, start + g);
    G2_LOAD(a1, u1, start + g + 4);
    for (int j = start + g; j < end; j += 8) {
        float na0, na1;
        unsigned nu0, nu1;
        G2_LOAD(na0, nu0, j + 8);
        G2_LOAD(na1, nu1, j + 12);
        {
            float xv = a0 + ad;
            float p = __expf(fmaxf(xv, NEG_SLOPE * xv));
            dsum += p;
            accx += p * blo(u0);
            accy += p * bhi(u0);
        }
        {
            float xv = a1 + ad;
            float p = __expf(fmaxf(xv, NEG_SLOPE * xv));
            dsum += p;
            accx += p * blo(u1);
            accy += p * bhi(u1);
        }
        a0 = na0; u0 = nu0; a1 = na1; u1 = nu1;
    }
#undef G2_LOAD
    dsum += __shfl_xor(dsum, 16); accx += __shfl_xor(accx, 16); accy += __shfl_xor(accy, 16);
    dsum += __shfl_xor(dsum, 32); accx += __shfl_xor(accx, 32); accy += __shfl_xor(accy, 32);
    const float inv = 1.f / (dsum + 1e-16f);
    const float2 b2v = *(const float2*)(b2 + 2 * c2);
    float ex = fmaxf(accx * inv + b2v.x, 0.f);
    float ey = fmaxf(accy * inv + b2v.y, 0.f);
    if (g == 0) *(float2*)(emb + (size_t)wid * 32 + 2 * c2) = make_float2(ex, ey);
    const int col = (lane < 40) ? lane : 0;
    float lsum = (lane < 40) ? fcb[col] : 0.f;
    #pragma unroll
    for (int k = 0; k < 16; ++k) {
        float vx = __shfl(ex, k);
        float vy = __shfl(ey, k);
        lsum += vx * sw[2 * k][col] + vy * sw[2 * k + 1][col];
    }
    if (lane < 40) logits[(size_t)wid * 40 + lane] = lsum;
}

// ---------- launch ----------
extern "C" void kernel_launch(void* const* d_in, const int* in_sizes, int n_in,
                              void* d_out, int out_size, void* d_ws, size_t ws_size,
                              hipStream_t stream)
{
    const float* x   = (const float*)d_in[0];
    const int*   ei  = (const int*)d_in[1];
    const float* W1  = (const float*)d_in[2];
    const float* as1 = (const float*)d_in[3];
    const float* ad1 = (const float*)d_in[4];
    const float* b1  = (const float*)d_in[5];
    const float* W2  = (const float*)d_in[6];
    const float* as2 = (const float*)d_in[7];
    const float* ad2 = (const float*)d_in[8];
    const float* b2  = (const float*)d_in[9];
    const float* fcW = (const float*)d_in[10];
    const float* fcb = (const float*)d_in[11];

    const int n  = in_sizes[0] / 256;   // 50000
    const int e  = in_sizes[1] / 2;     // 800000
    const int el = e + n;               // with self-loops

    char* ws = (char*)d_ws;
    size_t off = 0;
    unsigned short* w1t  = (unsigned short*)(ws + off); off += (size_t)512 * 256 * 2;
    unsigned short* w2t  = (unsigned short*)(ws + off); off += (size_t)32 * 512 * 2;
    unsigned char*  xl1q = (unsigned char*)(ws + off);  off += (size_t)n * 512;
    float* ascale = (float*)(ws + off); off += (size_t)n * 16 * 4;
    unsigned short* h1   = (unsigned short*)(ws + off); off += (size_t)n * 512 * 2;
    unsigned short* xl2b = (unsigned short*)(ws + off); off += (size_t)n * 32 * 2;
    float* a_dst1 = (float*)(ws + off); off += (size_t)n * 8 * 4;
    float* a_src2 = (float*)(ws + off); off += (size_t)n * 4;
    float* a_dst2 = (float*)(ws + off); off += (size_t)n * 4;
    int*   deg    = (int*)(ws + off);   off += (size_t)n * 16 * 4;   // padded: 1/line
    int*   cursor = (int*)(ws + off);   off += (size_t)n * 16 * 4;   // padded: 1/line
    int*   rowptr = (int*)(ws + off);   off += (size_t)(n + 1) * 4;
    int*   csr_off= (int*)(ws + off);   off += (size_t)el * 4;
    int*   bsum   = (int*)(ws + off);   off += 256 * 4;
    int*   bsoff  = (int*)(ws + off);   off += 256 * 4;

    float* emb    = (float*)d_out;
    float* logits = (float*)d_out + (size_t)n * 32;

    hipMemsetAsync(deg, 0, (size_t)n * 16 * 4, stream);

    const int b_cw = (512 * 256 + 32 * 512 + 255) / 256;
    const int b_dg = (el + 1023) / 1024;
    prep_kernel<<<b_cw + b_dg, 256, 0, stream>>>(
        W1, w1t, W2, w2t, ei, e, el, deg, b_cw);

    const int nb = (n + 255) / 256;
    scan1_kernel<<<nb, 256, 0, stream>>>(deg, bsum, n);
    scan2_kernel<<<1, 256, 0, stream>>>(bsum, bsoff, nb);
    scan3_kernel<<<nb, 256, 0, stream>>>(deg, bsoff, rowptr, cursor, n, el);

    const int b_sc = (el + 1023) / 1024;
    const int n_tiles_y = (n + 127) / 128;
    scatter_gemm1_kernel<<<b_sc + 4 * n_tiles_y, 256, 0, stream>>>(
        ei, e, el, cursor, csr_off,
        x, w1t, xl1q, ascale, as1, ad1, a_dst1, n, b_sc);

    gather1_kernel<<<((size_t)n * 64 + 255) / 256, 256, 0, stream>>>(
        rowptr, csr_off, xl1q, ascale, a_dst1, b1, h1, n);
    gemm2_mfma_kernel<<<(n + 127) / 128, 256, 0, stream>>>(
        h1, w2t, as2, ad2, xl2b, a_src2, a_dst2, n);
    gather2_head_kernel<<<((size_t)n * 64 + 255) / 256, 256, 0, stream>>>(
        rowptr, csr_off, xl2b, a_src2, a_dst2, b2, fcW, fcb, emb, logits, n);
}

// Round 10
// 363.841 us; speedup vs baseline: 1.1471x; 1.0747x over previous
//
#include <hip/hip_runtime.h>
#include <hip/hip_bf16.h>
#include <math.h>

#define NEG_SLOPE 0.2f

typedef __attribute__((ext_vector_type(8))) short bf16x8;
typedef __attribute__((ext_vector_type(4))) float f32x4;

__device__ __forceinline__ float lrelu(float x) { return fmaxf(x, NEG_SLOPE * x); }
__device__ __forceinline__ float blo(unsigned u) { return __uint_as_float(u << 16); }
__device__ __forceinline__ float bhi(unsigned u) { return __uint_as_float(u & 0xffff0000u); }
__device__ __forceinline__ unsigned short f2b(float f) {
    __hip_bfloat16 b = __float2bfloat16(f);
    return *(unsigned short*)&b;
}
// stored-order k -> true k (permutation within each 64-channel block; see R3 note)
__device__ __forceinline__ int ktrue(int k) {
    int pl = k & 63;
    return (k & ~63) + ((pl & 3) << 4) + (pl >> 2);
}

// R10: rank-in-prep -> atomic-free CSR scatter. The prep histogram and the
// scatter cursor performed the SAME 850k atomicAdds; prep discarded the return.
// Now prep captures it (rank[e]) and pass B is pure loads + one fire-and-forget
// store: csr_off[rowptr[d] + rank[e]] = s<<9. Device-wide atomic work unchanged
// (no R7-style conservation trap); the 100us kernel loses its dependent
// atomic-roundtrip->store chain. cursor deleted.

// ---------- prep: W1->W1T bf16, W2->W2T bf16 (k-permuted), deg histogram + rank ----------
__global__ __launch_bounds__(256) void prep_kernel(
    const float* __restrict__ W1, unsigned short* __restrict__ W1T,
    const float* __restrict__ W2, unsigned short* __restrict__ W2T,
    const int* __restrict__ ei, int E, int EL, int* __restrict__ deg,
    int* __restrict__ rank, int b_cw)
{
    const int b = blockIdx.x;
    if (b < b_cw) {
        int i = b * 256 + threadIdx.x;
        if (i < 512 * 256) {
            int nn = i >> 8, k = i & 255;
            W1T[nn * 256 + k] = f2b(W1[k * 512 + nn]);
        } else if (i < 512 * 256 + 32 * 512) {
            int j = i - 512 * 256;
            int c = j >> 9, k = j & 511;
            W2T[c * 512 + k] = f2b(W2[ktrue(k) * 32 + c]);
        }
    } else {
        // histogram with captured ranks: 4 returning atomics in flight/thread
        const int base = (b - b_cw) * 1024 + threadIdx.x;
        const int e0 = base, e1 = base + 256, e2 = base + 512, e3 = base + 768;
        const bool v0 = e0 < EL, v1 = e1 < EL, v2 = e2 < EL, v3 = e3 < EL;
        int d0 = 0, d1 = 0, d2 = 0, d3 = 0;
        if (v0) d0 = (e0 < E) ? ei[E + e0] : e0 - E;
        if (v1) d1 = (e1 < E) ? ei[E + e1] : e1 - E;
        if (v2) d2 = (e2 < E) ? ei[E + e2] : e2 - E;
        if (v3) d3 = (e3 < E) ? ei[E + e3] : e3 - E;
        int r0 = 0, r1 = 0, r2 = 0, r3 = 0;
        if (v0) r0 = atomicAdd(&deg[d0 << 4], 1);
        if (v1) r1 = atomicAdd(&deg[d1 << 4], 1);
        if (v2) r2 = atomicAdd(&deg[d2 << 4], 1);
        if (v3) r3 = atomicAdd(&deg[d3 << 4], 1);
        if (v0) rank[e0] = r0;
        if (v1) rank[e1] = r1;
        if (v2) rank[e2] = r2;
        if (v3) rank[e3] = r3;
    }
}

// ---------- two-level scan (reads padded deg) ----------
__global__ __launch_bounds__(256) void scan1_kernel(
    const int* __restrict__ deg, int* __restrict__ bsum, int n)
{
    __shared__ int red[256];
    int t = threadIdx.x, i = blockIdx.x * 256 + t;
    red[t] = (i < n) ? deg[i << 4] : 0;
    __syncthreads();
    for (int off = 128; off > 0; off >>= 1) {
        if (t < off) red[t] += red[t + off];
        __syncthreads();
    }
    if (t == 0) bsum[blockIdx.x] = red[0];
}

__global__ __launch_bounds__(256) void scan2_kernel(
    const int* __restrict__ bsum, int* __restrict__ bsoff, int B)
{
    __shared__ int part[256];
    int t = threadIdx.x;
    int v = (t < B) ? bsum[t] : 0;
    part[t] = v;
    __syncthreads();
    for (int off = 1; off < 256; off <<= 1) {
        int tmp = (t >= off) ? part[t - off] : 0;
        __syncthreads();
        part[t] += tmp;
        __syncthreads();
    }
    if (t < B) bsoff[t] = part[t] - v;
}

__global__ __launch_bounds__(256) void scan3_kernel(
    const int* __restrict__ deg, const int* __restrict__ bsoff,
    int* __restrict__ rowptr, int n, int EL)
{
    __shared__ int part[256];
    int t = threadIdx.x, b = blockIdx.x, i = b * 256 + t;
    int v = (i < n) ? deg[i << 4] : 0;
    part[t] = v;
    __syncthreads();
    for (int off = 1; off < 256; off <<= 1) {
        int tmp = (t >= off) ? part[t - off] : 0;
        __syncthreads();
        part[t] += tmp;
        __syncthreads();
    }
    if (i < n) rowptr[i] = bsoff[b] + part[t] - v;
    if (i == n - 1) rowptr[n] = EL;
}

// ---------- merged atomic-free CSR-scatter + GEMM1 ----------
// blocks [0, b_sc): scatter 1024 edges each. Per edge: coalesced ei+rank loads,
// one L2-resident rowptr[d] load, one fire-and-forget csr store. NO atomics.
// blocks [b_sc, ...): GEMM1 tiles (128x128, BK=32, rows padded 32->40, fused
// att1 dots, int8 quant epilogue -- R3). ascale = (a_src, scale) float2.
__global__ __launch_bounds__(256) void scatter_gemm1_kernel(
    const int* __restrict__ ei, int E, int EL,
    const int* __restrict__ rank, const int* __restrict__ rowptr,
    int* __restrict__ csr_off,
    const float* __restrict__ x, const unsigned short* __restrict__ W1T,
    unsigned char* __restrict__ xl1q, float* __restrict__ ascale,
    const float* __restrict__ att_src, const float* __restrict__ att_dst,
    float* __restrict__ a_dst,
    int M, int b_sc)
{
    if (blockIdx.x < b_sc) {
        const int base = blockIdx.x * 1024 + threadIdx.x;
        const int e0 = base, e1 = base + 256, e2 = base + 512, e3 = base + 768;
        const bool v0 = e0 < EL, v1 = e1 < EL, v2 = e2 < EL, v3 = e3 < EL;
        int s0 = 0, s1 = 0, s2 = 0, s3 = 0;
        int d0 = 0, d1 = 0, d2 = 0, d3 = 0;
        if (v0) { if (e0 < E) { s0 = ei[e0]; d0 = ei[E + e0]; } else s0 = d0 = e0 - E; }
        if (v1) { if (e1 < E) { s1 = ei[e1]; d1 = ei[E + e1]; } else s1 = d1 = e1 - E; }
        if (v2) { if (e2 < E) { s2 = ei[e2]; d2 = ei[E + e2]; } else s2 = d2 = e2 - E; }
        if (v3) { if (e3 < E) { s3 = ei[e3]; d3 = ei[E + e3]; } else s3 = d3 = e3 - E; }
        int r0 = 0, r1 = 0, r2 = 0, r3 = 0;
        if (v0) r0 = rank[e0];
        if (v1) r1 = rank[e1];
        if (v2) r2 = rank[e2];
        if (v3) r3 = rank[e3];
        int p0 = 0, p1 = 0, p2 = 0, p3 = 0;
        if (v0) p0 = rowptr[d0] + r0;
        if (v1) p1 = rowptr[d1] + r1;
        if (v2) p2 = rowptr[d2] + r2;
        if (v3) p3 = rowptr[d3] + r3;
        if (v0) csr_off[p0] = s0 << 9;
        if (v1) csr_off[p1] = s1 << 9;
        if (v2) csr_off[p2] = s2 << 9;
        if (v3) csr_off[p3] = s3 << 9;
        return;
    }
    __shared__ unsigned short As[128 * 40];
    __shared__ unsigned short Bs[128 * 40];
    const int tt  = blockIdx.x - b_sc;
    const int nt4 = gridDim.x - b_sc;
    int tr, tc;
    if (tt < (nt4 & ~31)) { tr = ((tt >> 5) << 3) + (tt & 7); tc = (tt >> 3) & 3; }
    else                  { tr = tt >> 2;                      tc = tt & 3; }
    const int row0 = tr * 128;
    const int col0 = tc * 128;
    const int tid  = threadIdx.x;
    const int wave = tid >> 6;
    const int wrow = wave >> 1;
    const int wcol = wave & 1;
    const int lane = tid & 63;
    const int quad = lane >> 4;
    const int l15  = lane & 15;
    const int sm = tid >> 1;
    const int sk = (tid & 1) * 16;

    f32x4 acc[4][4] = {};

    for (int kb = 0; kb < 256; kb += 32) {
        uint4 a0 = make_uint4(0, 0, 0, 0), a1 = make_uint4(0, 0, 0, 0);
        if (row0 + sm < M) {
            const float4* ap = (const float4*)(x + (size_t)(row0 + sm) * 256 + kb + sk);
            float4 f0 = ap[0], f1 = ap[1], f2 = ap[2], f3 = ap[3];
            a0.x = (unsigned)f2b(f0.x) | ((unsigned)f2b(f0.y) << 16);
            a0.y = (unsigned)f2b(f0.z) | ((unsigned)f2b(f0.w) << 16);
            a0.z = (unsigned)f2b(f1.x) | ((unsigned)f2b(f1.y) << 16);
            a0.w = (unsigned)f2b(f1.z) | ((unsigned)f2b(f1.w) << 16);
            a1.x = (unsigned)f2b(f2.x) | ((unsigned)f2b(f2.y) << 16);
            a1.y = (unsigned)f2b(f2.z) | ((unsigned)f2b(f2.w) << 16);
            a1.z = (unsigned)f2b(f3.x) | ((unsigned)f2b(f3.y) << 16);
            a1.w = (unsigned)f2b(f3.z) | ((unsigned)f2b(f3.w) << 16);
        }
        uint4* adp = (uint4*)&As[sm * 40 + sk];
        adp[0] = a0; adp[1] = a1;
        const uint4* bp = (const uint4*)(W1T + (size_t)(col0 + sm) * 256 + kb + sk);
        uint4* bd = (uint4*)&Bs[sm * 40 + sk];
        bd[0] = bp[0]; bd[1] = bp[1];
        __syncthreads();
        bf16x8 af[4], bf[4];
        #pragma unroll
        for (int mf = 0; mf < 4; ++mf)
            af[mf] = *(const bf16x8*)&As[(wrow * 64 + mf * 16 + l15) * 40 + quad * 8];
        #pragma unroll
        for (int nf = 0; nf < 4; ++nf)
            bf[nf] = *(const bf16x8*)&Bs[(wcol * 64 + nf * 16 + l15) * 40 + quad * 8];
        #pragma unroll
        for (int mf = 0; mf < 4; ++mf)
            #pragma unroll
            for (int nf = 0; nf < 4; ++nf)
                acc[mf][nf] = __builtin_amdgcn_mfma_f32_16x16x32_bf16(
                    af[mf], bf[nf], acc[mf][nf], 0, 0, 0);
        __syncthreads();
    }

    const int h = tc * 2 + wcol;   // head index == 64-col chunk index
    float asv[4], adv[4];
    #pragma unroll
    for (int nf = 0; nf < 4; ++nf) {
        asv[nf] = att_src[h * 64 + nf * 16 + l15];
        adv[nf] = att_dst[h * 64 + nf * 16 + l15];
    }
    #pragma unroll
    for (int mf = 0; mf < 4; ++mf) {
        #pragma unroll
        for (int r = 0; r < 4; ++r) {
            const int row = row0 + wrow * 64 + mf * 16 + quad * 4 + r;
            float v0 = acc[mf][0][r], v1 = acc[mf][1][r];
            float v2 = acc[mf][2][r], v3 = acc[mf][3][r];
            float sv = v0 * asv[0] + v1 * asv[1] + v2 * asv[2] + v3 * asv[3];
            float tv = v0 * adv[0] + v1 * adv[1] + v2 * adv[2] + v3 * adv[3];
            sv += __shfl_xor(sv, 1); tv += __shfl_xor(tv, 1);
            sv += __shfl_xor(sv, 2); tv += __shfl_xor(tv, 2);
            sv += __shfl_xor(sv, 4); tv += __shfl_xor(tv, 4);
            sv += __shfl_xor(sv, 8); tv += __shfl_xor(tv, 8);
            // per-(row, 64-col) absmax across the 16 lanes of this quad
            float m4 = fmaxf(fmaxf(fabsf(v0), fabsf(v1)), fmaxf(fabsf(v2), fabsf(v3)));
            m4 = fmaxf(m4, __shfl_xor(m4, 1));
            m4 = fmaxf(m4, __shfl_xor(m4, 2));
            m4 = fmaxf(m4, __shfl_xor(m4, 4));
            m4 = fmaxf(m4, __shfl_xor(m4, 8));
            const float invs = (m4 > 0.f) ? 127.f / m4 : 0.f;
            int q0 = __float2int_rn(v0 * invs); q0 = max(-127, min(127, q0));
            int q1 = __float2int_rn(v1 * invs); q1 = max(-127, min(127, q1));
            int q2 = __float2int_rn(v2 * invs); q2 = max(-127, min(127, q2));
            int q3 = __float2int_rn(v3 * invs); q3 = max(-127, min(127, q3));
            unsigned pkq = (unsigned)(q0 + 128) | ((unsigned)(q1 + 128) << 8) |
                           ((unsigned)(q2 + 128) << 16) | ((unsigned)(q3 + 128) << 24);
            if (row < M) {
                *(unsigned*)(xl1q + (size_t)row * 512 + h * 64 + l15 * 4) = pkq;
                if (l15 == 0) {
                    *(float2*)(ascale + (size_t)row * 16 + h * 2) =
                        make_float2(sv, m4 * (1.f / 127.f));
                    a_dst[row * 8 + h] = tv;
                }
            }
        }
    }
}

// ---------- fused layer-1 softmax + aggregate + bias + relu -> h1 (bf16) ----------
// depth-4 register pipeline (R6 sweet spot: 32 VGPR, ~67% occupancy; depth 6
// regressed via occupancy loss -- R8). Byte-offset csr addressing.
__global__ __launch_bounds__(256) void gather1_kernel(
    const int* __restrict__ rowptr, const int* __restrict__ csr_off,
    const unsigned char* __restrict__ xl1q, const float* __restrict__ ascale,
    const float* __restrict__ a_dst, const float* __restrict__ b1,
    unsigned short* __restrict__ h1, int M)
{
    int wid  = (blockIdx.x * blockDim.x + threadIdx.x) >> 6;
    int lane = threadIdx.x & 63;
    if (wid >= M) return;
    const int start = rowptr[wid], end = rowptr[wid + 1];
    const int h0 = lane >> 3;   // chunk index == head for this lane's 8 channels
    const float adh = a_dst[wid * 8 + h0];
    const char* asbase = (const char*)ascale + (h0 << 3);
    const unsigned char* xbase = xl1q + (lane << 3);
    float dsum = 0.f, csum = 0.f;
    float acc0 = 0.f, acc1 = 0.f, acc2 = 0.f, acc3 = 0.f;
    float acc4 = 0.f, acc5 = 0.f, acc6 = 0.f, acc7 = 0.f;

#define G1_LOAD(AS, V, idx) do {                                              \
        if ((idx) < end) {                                                    \
            int o_ = csr_off[idx];                                            \
            AS = *(const float2*)(asbase + (o_ >> 3));                        \
            V  = *(const uint2*)(xbase + o_);                                 \
        } else { AS = make_float2(-1e30f, 0.f); V = make_uint2(0u, 0u); }     \
    } while (0)

#define G1_CONS(AS, V) do {                                                   \
        float x_ = (AS).x + adh;                                              \
        float p_ = __expf(fmaxf(x_, NEG_SLOPE * x_));                         \
        dsum += p_;                                                           \
        float sa_ = p_ * (AS).y;                                              \
        csum += sa_;                                                          \
        acc0 += (float)( (V).x        & 0xffu) * sa_;                         \
        acc1 += (float)(((V).x >>  8) & 0xffu) * sa_;                         \
        acc2 += (float)(((V).x >> 16) & 0xffu) * sa_;                         \
        acc3 += (float)( (V).x >> 24         ) * sa_;                         \
        acc4 += (float)( (V).y        & 0xffu) * sa_;                         \
        acc5 += (float)(((V).y >>  8) & 0xffu) * sa_;                         \
        acc6 += (float)(((V).y >> 16) & 0xffu) * sa_;                         \
        acc7 += (float)( (V).y >> 24         ) * sa_;                         \
    } while (0)

    float2 as0, as1, as2, as3;
    uint2  v0, v1, v2, v3;
    G1_LOAD(as0, v0, start);
    G1_LOAD(as1, v1, start + 1);
    G1_LOAD(as2, v2, start + 2);
    G1_LOAD(as3, v3, start + 3);
    for (int j = start; j < end; j += 4) {
        float2 na0, na1, na2, na3;
        uint2  nv0, nv1, nv2, nv3;
        G1_LOAD(na0, nv0, j + 4);
        G1_LOAD(na1, nv1, j + 5);
        G1_LOAD(na2, nv2, j + 6);
        G1_LOAD(na3, nv3, j + 7);
        G1_CONS(as0, v0);
        G1_CONS(as1, v1);
        G1_CONS(as2, v2);
        G1_CONS(as3, v3);
        as0 = na0; v0 = nv0; as1 = na1; v1 = nv1;
        as2 = na2; v2 = nv2; as3 = na3; v3 = nv3;
    }
#undef G1_LOAD
#undef G1_CONS

    const float inv = 1.f / (dsum + 1e-16f);
    const float c128 = 128.f * csum;
    // bias through the stored-order permutation
    const int pg = lane << 3;
    float bj[8];
    #pragma unroll
    for (int j = 0; j < 8; ++j) {
        int pl = (pg + j) & 63;
        bj[j] = b1[(pg & ~63) + ((pl & 3) << 4) + (pl >> 2)];
    }
    float o0 = fmaxf((acc0 - c128) * inv + bj[0], 0.f);
    float o1 = fmaxf((acc1 - c128) * inv + bj[1], 0.f);
    float o2 = fmaxf((acc2 - c128) * inv + bj[2], 0.f);
    float o3 = fmaxf((acc3 - c128) * inv + bj[3], 0.f);
    float o4 = fmaxf((acc4 - c128) * inv + bj[4], 0.f);
    float o5 = fmaxf((acc5 - c128) * inv + bj[5], 0.f);
    float o6 = fmaxf((acc6 - c128) * inv + bj[6], 0.f);
    float o7 = fmaxf((acc7 - c128) * inv + bj[7], 0.f);
    uint4 pk;
    pk.x = (unsigned)f2b(o0) | ((unsigned)f2b(o1) << 16);
    pk.y = (unsigned)f2b(o2) | ((unsigned)f2b(o3) << 16);
    pk.z = (unsigned)f2b(o4) | ((unsigned)f2b(o5) << 16);
    pk.w = (unsigned)f2b(o6) | ((unsigned)f2b(o7) << 16);
    ((uint4*)(h1 + (size_t)wid * 512))[lane] = pk;
}

// ---------- GEMM2 (MFMA bf16): xl2[M,32] = h1[M,512] @ W2; fused att2 dots ----------
__global__ __launch_bounds__(256) void gemm2_mfma_kernel(
    const unsigned short* __restrict__ h1, const unsigned short* __restrict__ W2T,
    const float* __restrict__ att_src2, const float* __restrict__ att_dst2,
    unsigned short* __restrict__ xl2b, float* __restrict__ a_src2, float* __restrict__ a_dst2,
    int M)
{
    __shared__ unsigned short As[128 * 72];
    __shared__ unsigned short Bs[32 * 72];
    const int tid  = threadIdx.x;
    const int row0 = blockIdx.x * 128;
    const int wv   = tid >> 6;
    const int lane = tid & 63;
    const int quad = lane >> 4;
    const int l15  = lane & 15;

    f32x4 acc[2][2] = {};

    for (int kb = 0; kb < 512; kb += 64) {
        #pragma unroll
        for (int i = 0; i < 4; ++i) {
            int u = tid + 256 * i;
            int r = u >> 3;
            int kq = (u & 7) * 8;
            uint4 v = make_uint4(0, 0, 0, 0);
            if (row0 + r < M)
                v = *(const uint4*)(h1 + (size_t)(row0 + r) * 512 + kb + kq);
            *(uint4*)&As[r * 72 + kq] = v;
        }
        {
            int r = tid >> 3;
            int kq = (tid & 7) * 8;
            *(uint4*)&Bs[r * 72 + kq] = *(const uint4*)(W2T + (size_t)r * 512 + kb + kq);
        }
        __syncthreads();

        #pragma unroll
        for (int ks = 0; ks < 2; ++ks) {
            bf16x8 af[2], bf[2];
            #pragma unroll
            for (int mf = 0; mf < 2; ++mf)
                af[mf] = *(const bf16x8*)&As[(wv * 32 + mf * 16 + l15) * 72 + ks * 32 + quad * 8];
            #pragma unroll
            for (int nf = 0; nf < 2; ++nf)
                bf[nf] = *(const bf16x8*)&Bs[(nf * 16 + l15) * 72 + ks * 32 + quad * 8];
            #pragma unroll
            for (int mf = 0; mf < 2; ++mf)
                #pragma unroll
                for (int nf = 0; nf < 2; ++nf)
                    acc[mf][nf] = __builtin_amdgcn_mfma_f32_16x16x32_bf16(
                        af[mf], bf[nf], acc[mf][nf], 0, 0, 0);
        }
        __syncthreads();
    }

    float as2v[2], ad2v[2];
    #pragma unroll
    for (int nf = 0; nf < 2; ++nf) {
        as2v[nf] = att_src2[nf * 16 + l15];
        ad2v[nf] = att_dst2[nf * 16 + l15];
    }
    #pragma unroll
    for (int mf = 0; mf < 2; ++mf) {
        #pragma unroll
        for (int r = 0; r < 4; ++r) {
            const int row = row0 + wv * 32 + mf * 16 + quad * 4 + r;
            float v0 = acc[mf][0][r], v1 = acc[mf][1][r];
            float sv = v0 * as2v[0] + v1 * as2v[1];
            float tv = v0 * ad2v[0] + v1 * ad2v[1];
            sv += __shfl_xor(sv, 1); tv += __shfl_xor(tv, 1);
            sv += __shfl_xor(sv, 2); tv += __shfl_xor(tv, 2);
            sv += __shfl_xor(sv, 4); tv += __shfl_xor(tv, 4);
            sv += __shfl_xor(sv, 8); tv += __shfl_xor(tv, 8);
            if (row < M) {
                xl2b[(size_t)row * 32 + l15]      = f2b(v0);
                xl2b[(size_t)row * 32 + 16 + l15] = f2b(v1);
                if (l15 == 0) { a_src2[row] = sv; a_dst2[row] = tv; }
            }
        }
    }
}

// ---------- fused layer-2 softmax + aggregate + bias + relu + fc head ----------
// depth-2 prefetch per edge-slot group; byte-offset csr addressing.
__global__ __launch_bounds__(256) void gather2_head_kernel(
    const int* __restrict__ rowptr, const int* __restrict__ csr_off,
    const unsigned short* __restrict__ xl2b, const float* __restrict__ a_src2,
    const float* __restrict__ a_dst2, const float* __restrict__ b2,
    const float* __restrict__ fcW, const float* __restrict__ fcb,
    float* __restrict__ emb, float* __restrict__ logits, int M)
{
    __shared__ float sw[32][40];
    for (int i = threadIdx.x; i < 32 * 40; i += 256) sw[i / 40][i % 40] = fcW[i];
    __syncthreads();
    int wid  = (blockIdx.x * blockDim.x + threadIdx.x) >> 6;
    int lane = threadIdx.x & 63;
    if (wid >= M) return;
    const int start = rowptr[wid], end = rowptr[wid + 1];
    const float ad = a_dst2[wid];
    const int g  = lane >> 4;        // 0..3: edge slot
    const int c2 = lane & 15;        // channel pair
    const char* xbase = (const char*)xl2b + (c2 << 2);

#define G2_LOAD(A, U, idx) do {                                               \
        if ((idx) < end) {                                                    \
            int o_ = csr_off[idx];                                            \
            A = *(const float*)((const char*)a_src2 + (o_ >> 7));             \
            U = *(const unsigned*)(xbase + (o_ >> 3));                        \
        } else { A = -1e30f; U = 0u; }                                        \
    } while (0)

    float dsum = 0.f;
    float accx = 0.f, accy = 0.f;
    float a0, a1;
    unsigned u0, u1;
    G2_LOAD(a0, u0, start + g);
    G2_LOAD(a1, u1, start + g + 4);
    for (int j = start + g; j < end; j += 8) {
        float na0, na1;
        unsigned nu0, nu1;
        G2_LOAD(na0, nu0, j + 8);
        G2_LOAD(na1, nu1, j + 12);
        {
            float xv = a0 + ad;
            float p = __expf(fmaxf(xv, NEG_SLOPE * xv));
            dsum += p;
            accx += p * blo(u0);
            accy += p * bhi(u0);
        }
        {
            float xv = a1 + ad;
            float p = __expf(fmaxf(xv, NEG_SLOPE * xv));
            dsum += p;
            accx += p * blo(u1);
            accy += p * bhi(u1);
        }
        a0 = na0; u0 = nu0; a1 = na1; u1 = nu1;
    }
#undef G2_LOAD
    dsum += __shfl_xor(dsum, 16); accx += __shfl_xor(accx, 16); accy += __shfl_xor(accy, 16);
    dsum += __shfl_xor(dsum, 32); accx += __shfl_xor(accx, 32); accy += __shfl_xor(accy, 32);
    const float inv = 1.f / (dsum + 1e-16f);
    const float2 b2v = *(const float2*)(b2 + 2 * c2);
    float ex = fmaxf(accx * inv + b2v.x, 0.f);
    float ey = fmaxf(accy * inv + b2v.y, 0.f);
    if (g == 0) *(float2*)(emb + (size_t)wid * 32 + 2 * c2) = make_float2(ex, ey);
    const int col = (lane < 40) ? lane : 0;
    float lsum = (lane < 40) ? fcb[col] : 0.f;
    #pragma unroll
    for (int k = 0; k < 16; ++k) {
        float vx = __shfl(ex, k);
        float vy = __shfl(ey, k);
        lsum += vx * sw[2 * k][col] + vy * sw[2 * k + 1][col];
    }
    if (lane < 40) logits[(size_t)wid * 40 + lane] = lsum;
}

// ---------- launch ----------
extern "C" void kernel_launch(void* const* d_in, const int* in_sizes, int n_in,
                              void* d_out, int out_size, void* d_ws, size_t ws_size,
                              hipStream_t stream)
{
    const float* x   = (const float*)d_in[0];
    const int*   ei  = (const int*)d_in[1];
    const float* W1  = (const float*)d_in[2];
    const float* as1 = (const float*)d_in[3];
    const float* ad1 = (const float*)d_in[4];
    const float* b1  = (const float*)d_in[5];
    const float* W2  = (const float*)d_in[6];
    const float* as2 = (const float*)d_in[7];
    const float* ad2 = (const float*)d_in[8];
    const float* b2  = (const float*)d_in[9];
    const float* fcW = (const float*)d_in[10];
    const float* fcb = (const float*)d_in[11];

    const int n  = in_sizes[0] / 256;   // 50000
    const int e  = in_sizes[1] / 2;     // 800000
    const int el = e + n;               // with self-loops

    char* ws = (char*)d_ws;
    size_t off = 0;
    unsigned short* w1t  = (unsigned short*)(ws + off); off += (size_t)512 * 256 * 2;
    unsigned short* w2t  = (unsigned short*)(ws + off); off += (size_t)32 * 512 * 2;
    unsigned char*  xl1q = (unsigned char*)(ws + off);  off += (size_t)n * 512;
    float* ascale = (float*)(ws + off); off += (size_t)n * 16 * 4;
    unsigned short* h1   = (unsigned short*)(ws + off); off += (size_t)n * 512 * 2;
    unsigned short* xl2b = (unsigned short*)(ws + off); off += (size_t)n * 32 * 2;
    float* a_dst1 = (float*)(ws + off); off += (size_t)n * 8 * 4;
    float* a_src2 = (float*)(ws + off); off += (size_t)n * 4;
    float* a_dst2 = (float*)(ws + off); off += (size_t)n * 4;
    int*   deg    = (int*)(ws + off);   off += (size_t)n * 16 * 4;   // padded: 1/line
    int*   rank   = (int*)(ws + off);   off += (size_t)el * 4;
    int*   rowptr = (int*)(ws + off);   off += (size_t)(n + 1) * 4;
    int*   csr_off= (int*)(ws + off);   off += (size_t)el * 4;
    int*   bsum   = (int*)(ws + off);   off += 256 * 4;
    int*   bsoff  = (int*)(ws + off);   off += 256 * 4;

    float* emb    = (float*)d_out;
    float* logits = (float*)d_out + (size_t)n * 32;

    hipMemsetAsync(deg, 0, (size_t)n * 16 * 4, stream);

    const int b_cw = (512 * 256 + 32 * 512 + 255) / 256;
    const int b_dg = (el + 1023) / 1024;
    prep_kernel<<<b_cw + b_dg, 256, 0, stream>>>(
        W1, w1t, W2, w2t, ei, e, el, deg, rank, b_cw);

    const int nb = (n + 255) / 256;
    scan1_kernel<<<nb, 256, 0, stream>>>(deg, bsum, n);
    scan2_kernel<<<1, 256, 0, stream>>>(bsum, bsoff, nb);
    scan3_kernel<<<nb, 256, 0, stream>>>(deg, bsoff, rowptr, n, el);

    const int b_sc = (el + 1023) / 1024;
    const int n_tiles_y = (n + 127) / 128;
    scatter_gemm1_kernel<<<b_sc + 4 * n_tiles_y, 256, 0, stream>>>(
        ei, e, el, rank, rowptr, csr_off,
        x, w1t, xl1q, ascale, as1, ad1, a_dst1, n, b_sc);

    gather1_kernel<<<((size_t)n * 64 + 255) / 256, 256, 0, stream>>>(
        rowptr, csr_off, xl1q, ascale, a_dst1, b1, h1, n);
    gemm2_mfma_kernel<<<(n + 127) / 128, 256, 0, stream>>>(
        h1, w2t, as2, ad2, xl2b, a_src2, a_dst2, n);
    gather2_head_kernel<<<((size_t)n * 64 + 255) / 256, 256, 0, stream>>>(
        rowptr, csr_off, xl2b, a_src2, a_dst2, b2, fcW, fcb, emb, logits, n);
}